// Round 7
// baseline (2397.506 us; speedup 1.0000x reference)
//
#include <hip/hip_runtime.h>
#include <hip/hip_bf16.h>

namespace {

constexpr int CB   = 32;            // batch
constexpr int CS   = 64;            // seq len
constexpr int CDIN = 256;           // encoder hidden
constexpr int CH   = 256;           // LSTM hidden / GAT feature
constexpr int CE   = 128;           // embedding dim
constexpr int CV   = 128;           // vocab
constexpr int CGH  = 64;            // per-head GAT dim
constexpr int CNH  = 4;             // heads
constexpr int CN   = 128;           // graph nodes
constexpr int CDX  = CDIN + CE;     // 384 LSTM input
constexpr int CG   = 4 * CH;        // 1024 gates
constexpr int CM   = CB * CS;       // 2048 tokens

typedef _Float16 f16x2 __attribute__((ext_vector_type(2)));
typedef _Float16 f16x8 __attribute__((ext_vector_type(8)));
typedef float    f32x4 __attribute__((ext_vector_type(4)));

__device__ __forceinline__ float leakyf(float x) { return x >= 0.f ? x : 0.2f * x; }
__device__ __forceinline__ float eluf(float x)   { return x > 0.f ? x : expm1f(x); }
__device__ __forceinline__ float sigmf(float x)  { return 1.f / (1.f + expf(-x)); }
__device__ __forceinline__ float wredf(float v) {
  #pragma unroll
  for (int off = 32; off; off >>= 1) v += __shfl_xor(v, off);
  return v;
}
__device__ __forceinline__ f16x2 u2h(unsigned u) { union { unsigned u; f16x2 h; } x; x.u = u; return x.h; }
__device__ __forceinline__ unsigned h2u(f16x2 h) { union { f16x2 h; unsigned u; } x; x.h = h; return x.u; }

// x[m, 0:256] = hidden[b,s,:]; x[m, 256:384] = (s==0 ? init : embedding[forced[b,s-1]])
__global__ void k_build_x(const float* __restrict__ hidden, const int* __restrict__ forced,
                          const float* __restrict__ emb, const float* __restrict__ initt,
                          float* __restrict__ x) {
  int idx = blockIdx.x * 256 + threadIdx.x;
  if (idx >= CM * CDX) return;
  int m = idx / CDX, d = idx - m * CDX;
  float v;
  if (d < CDIN) {
    v = hidden[m * CDIN + d];
  } else {
    int e = d - CDIN;
    v = (m % CS == 0) ? initt[e] : emb[forced[m - 1] * CE + e];
  }
  x[idx] = v;
}

// Pack W_hh [1024 rows][256 k] fp32 into 4 regions keyed to k_lstm6's thread layout.
// Row r = gate t*256 + unit j; pair q in [0,128). Regions per gate:
//   q in [0,60)   -> Wa (AGPR),  f16x8 chunks [(t*15+q/4)*256+j]
//   q in [60,92)  -> Wv (VGPR),  f16x8 chunks [(t*8+(q-60)/4)*256+j]
//   q in [92,104) -> Wd (LDS),   uint2 pairs  [(t*6+(q-92)/2)*256+j]
//   q in [104,128)-> Ws (stream),f16x8 chunks [(t*6+(q-104)/4)*256+j]
__global__ void k_whh_pack3(const float* __restrict__ Whh, f16x2* __restrict__ Wa,
                            f16x2* __restrict__ Wv, f16x2* __restrict__ Wd,
                            f16x2* __restrict__ Ws) {
  int r = blockIdx.x;               // 0..1023
  int t = r >> 8, j = r & 255;
  int c = threadIdx.x;              // 0..63
  const float2* row = (const float2*)(Whh + r * CH);
  #pragma unroll
  for (int h = 0; h < 2; ++h) {
    int q = c + 64 * h;
    float2 wp = row[q];
    f16x2 w = { (_Float16)wp.x, (_Float16)wp.y };
    if (q < 60)       Wa[((t * 15 + (q >> 2)) * 256 + j) * 4 + (q & 3)] = w;
    else if (q < 92)  Wv[((t * 8 + ((q - 60) >> 2)) * 256 + j) * 4 + ((q - 60) & 3)] = w;
    else if (q < 104) Wd[((t * 6 + ((q - 92) >> 1)) * 256 + j) * 2 + ((q - 92) & 1)] = w;
    else              Ws[((t * 6 + ((q - 104) >> 2)) * 256 + j) * 4 + ((q - 104) & 3)] = w;
  }
}

// hint[k][i][c] = intent[i] . Wh[k][:,c];  f1int/f2int reductions
__global__ void k_hint(const float* __restrict__ intent, const float* __restrict__ Wh,
                       const float* __restrict__ ah, float* __restrict__ hint,
                       float* __restrict__ f1int, float* __restrict__ f2int) {
  int k = blockIdx.x / 127;
  int i = blockIdx.x % 127;
  int c = threadIdx.x;  // 64 threads
  float acc = 0.f;
  for (int d = 0; d < CH; ++d)
    acc += intent[i * CH + d] * Wh[(k * CH + d) * CGH + c];
  hint[(k * 128 + i) * CGH + c] = acc;
  float r1 = wredf(acc * ah[k * 128 + c]);
  float r2 = wredf(acc * ah[k * 128 + 64 + c]);
  if (c == 0) { f1int[k * 128 + i] = r1; f2int[k * 128 + i] = r2; }
}

__global__ void k_woao(const float* __restrict__ Wo, const float* __restrict__ ao,
                       float* __restrict__ woao1, float* __restrict__ woao2) {
  int t = threadIdx.x;  // 512 threads
  if (t < CH) {
    float acc = 0.f;
    for (int c = 0; c < CH; ++c) acc += Wo[t * CH + c] * ao[c];
    woao1[t] = acc;
  } else {
    int tt = t - CH;
    float acc = 0.f;
    for (int c = 0; c < CH; ++c) acc += Wo[tt * CH + c] * ao[CH + c];
    woao2[tt] = acc;
  }
}

// xg[m,g] = x[m,:] . W_ih[g,:] + b_ih[g] + b_hh[g]
__global__ void k_xg2(const float* __restrict__ x, const float* __restrict__ Wih,
                      const float* __restrict__ bih, const float* __restrict__ bhh,
                      float* __restrict__ xg) {
  __shared__ f32x4 xs[8][CDX / 4];  // 12 KB
  int m0 = blockIdx.x * 8;
  int tid = threadIdx.x;
  for (int idx = tid; idx < 8 * (CDX / 4); idx += 256) {
    int r = idx / (CDX / 4), q = idx - r * (CDX / 4);
    xs[r][q] = ((const f32x4*)x)[(m0 + r) * (CDX / 4) + q];
  }
  __syncthreads();
  int g0 = tid * 4;
  float acc[8][4];
  #pragma unroll
  for (int r = 0; r < 8; ++r)
    #pragma unroll
    for (int jj = 0; jj < 4; ++jj) acc[r][jj] = 0.f;
  const f32x4* w0 = (const f32x4*)(Wih + (g0 + 0) * CDX);
  const f32x4* w1 = (const f32x4*)(Wih + (g0 + 1) * CDX);
  const f32x4* w2 = (const f32x4*)(Wih + (g0 + 2) * CDX);
  const f32x4* w3 = (const f32x4*)(Wih + (g0 + 3) * CDX);
  #pragma unroll 2
  for (int q = 0; q < CDX / 4; ++q) {
    f32x4 wa = w0[q], wb = w1[q], wc = w2[q], wd = w3[q];
    #pragma unroll
    for (int r = 0; r < 8; ++r) {
      f32x4 xv = xs[r][q];
      acc[r][0] += wa.x * xv.x + wa.y * xv.y + wa.z * xv.z + wa.w * xv.w;
      acc[r][1] += wb.x * xv.x + wb.y * xv.y + wb.z * xv.z + wb.w * xv.w;
      acc[r][2] += wc.x * xv.x + wc.y * xv.y + wc.z * xv.z + wc.w * xv.w;
      acc[r][3] += wd.x * xv.x + wd.y * xv.y + wd.z * xv.z + wd.w * xv.w;
    }
  }
  f32x4 bias = { bih[g0] + bhh[g0], bih[g0 + 1] + bhh[g0 + 1],
                 bih[g0 + 2] + bhh[g0 + 2], bih[g0 + 3] + bhh[g0 + 3] };
  #pragma unroll
  for (int r = 0; r < 8; ++r) {
    f32x4 st = { acc[r][0] + bias.x, acc[r][1] + bias.y,
                 acc[r][2] + bias.z, acc[r][3] + bias.w };
    ((f32x4*)xg)[((m0 + r) * CG + g0) / 4] = st;
  }
}

#define F2(a, b, c) __builtin_amdgcn_fdot2((a), (b), (c), false)
#define PAIR0(v) __builtin_shufflevector((v), (v), 0, 1)
#define PAIR1(v) __builtin_shufflevector((v), (v), 2, 3)
#define PAIR2(v) __builtin_shufflevector((v), (v), 4, 5)
#define PAIR3(v) __builtin_shufflevector((v), (v), 6, 7)
#define AWRITE(dst, src) asm volatile("v_accvgpr_write_b32 %0, %1" : "=a"(dst) : "v"(src))
#define AREAD(dst, src)  asm volatile("v_accvgpr_read_b32 %0, %1" : "=v"(dst) : "a"(src))
#define VPIN(dst, src)   asm volatile("v_mov_b32 %0, %1" : "=v"(dst) : "v"(src))

// AGPR fill: gate array W, gate index TT, chunk Q4
#define AFILL(W, TT, Q4) { f16x8 v = wap[((TT) * 15 + (Q4)) * 256 + j];               \
  AWRITE(W[(Q4) * 4 + 0], h2u(PAIR0(v))); AWRITE(W[(Q4) * 4 + 1], h2u(PAIR1(v)));    \
  AWRITE(W[(Q4) * 4 + 2], h2u(PAIR2(v))); AWRITE(W[(Q4) * 4 + 3], h2u(PAIR3(v))); }
#define AFILL_G(W, TT) AFILL(W,TT,0) AFILL(W,TT,1) AFILL(W,TT,2) AFILL(W,TT,3) AFILL(W,TT,4) \
  AFILL(W,TT,5) AFILL(W,TT,6) AFILL(W,TT,7) AFILL(W,TT,8) AFILL(W,TT,9) AFILL(W,TT,10) \
  AFILL(W,TT,11) AFILL(W,TT,12) AFILL(W,TT,13) AFILL(W,TT,14)

#define VFILL(W, TT, Q4) { f16x8 v = wvp[((TT) * 8 + (Q4)) * 256 + j];                \
  VPIN(W[(Q4) * 4 + 0], h2u(PAIR0(v))); VPIN(W[(Q4) * 4 + 1], h2u(PAIR1(v)));         \
  VPIN(W[(Q4) * 4 + 2], h2u(PAIR2(v))); VPIN(W[(Q4) * 4 + 3], h2u(PAIR3(v))); }
#define VFILL_G(W, TT) VFILL(W,TT,0) VFILL(W,TT,1) VFILL(W,TT,2) VFILL(W,TT,3) \
  VFILL(W,TT,4) VFILL(W,TT,5) VFILL(W,TT,6) VFILL(W,TT,7)

// AGPR-region: 4 gates, one pair index q, shared h pair
#define AG4(q, hp) { unsigned u0, u1, u2, u3;                                          \
  AREAD(u0, wA0[q]); AREAD(u1, wA1[q]); AREAD(u2, wA2[q]); AREAD(u3, wA3[q]);          \
  acc0 = F2(u2h(u0), (hp), acc0); acc1 = F2(u2h(u1), (hp), acc1);                      \
  acc2 = F2(u2h(u2), (hp), acc2); acc3 = F2(u2h(u3), (hp), acc3); }
#define AGCHUNK(jc) { f16x8 hv = hs[jc];                                               \
  AG4((jc)*4+0, PAIR0(hv)); AG4((jc)*4+1, PAIR1(hv));                                  \
  AG4((jc)*4+2, PAIR2(hv)); AG4((jc)*4+3, PAIR3(hv)); }

#define VG4(q, hp) {                                                                   \
  acc0 = F2(u2h(wV0[q]), (hp), acc0); acc1 = F2(u2h(wV1[q]), (hp), acc1);              \
  acc2 = F2(u2h(wV2[q]), (hp), acc2); acc3 = F2(u2h(wV3[q]), (hp), acc3); }
#define VGCHUNK(jc, base) { f16x8 hv = hs[jc];                                         \
  VG4((base)+0, PAIR0(hv)); VG4((base)+1, PAIR1(hv));                                  \
  VG4((base)+2, PAIR2(hv)); VG4((base)+3, PAIR3(hv)); }

#define LD4(qh, hp0, hp1) {                                                            \
  uint2 dA = wl[(qh) * 256 + j];        uint2 dB = wl[(6 + (qh)) * 256 + j];           \
  uint2 dC = wl[(12 + (qh)) * 256 + j]; uint2 dD = wl[(18 + (qh)) * 256 + j];          \
  acc0 = F2(u2h(dA.x), (hp0), acc0); acc0 = F2(u2h(dA.y), (hp1), acc0);                \
  acc1 = F2(u2h(dB.x), (hp0), acc1); acc1 = F2(u2h(dB.y), (hp1), acc1);                \
  acc2 = F2(u2h(dC.x), (hp0), acc2); acc2 = F2(u2h(dC.y), (hp1), acc2);                \
  acc3 = F2(u2h(dD.x), (hp0), acc3); acc3 = F2(u2h(dD.y), (hp1), acc3); }

#define ST4(ch) { f16x8 hv = hs[26 + (ch)];                                            \
  f16x8 s0 = wsp[(ch) * 256 + j];        f16x8 s1 = wsp[(6 + (ch)) * 256 + j];         \
  f16x8 s2 = wsp[(12 + (ch)) * 256 + j]; f16x8 s3 = wsp[(18 + (ch)) * 256 + j];        \
  acc0 = F2(PAIR0(s0), PAIR0(hv), acc0); acc0 = F2(PAIR1(s0), PAIR1(hv), acc0);        \
  acc0 = F2(PAIR2(s0), PAIR2(hv), acc0); acc0 = F2(PAIR3(s0), PAIR3(hv), acc0);        \
  acc1 = F2(PAIR0(s1), PAIR0(hv), acc1); acc1 = F2(PAIR1(s1), PAIR1(hv), acc1);        \
  acc1 = F2(PAIR2(s1), PAIR2(hv), acc1); acc1 = F2(PAIR3(s1), PAIR3(hv), acc1);        \
  acc2 = F2(PAIR0(s2), PAIR0(hv), acc2); acc2 = F2(PAIR1(s2), PAIR1(hv), acc2);        \
  acc2 = F2(PAIR2(s2), PAIR2(hv), acc2); acc2 = F2(PAIR3(s2), PAIR3(hv), acc2);        \
  acc3 = F2(PAIR0(s3), PAIR0(hv), acc3); acc3 = F2(PAIR1(s3), PAIR1(hv), acc3);        \
  acc3 = F2(PAIR2(s3), PAIR2(hv), acc3); acc3 = F2(PAIR3(s3), PAIR3(hv), acc3); }

// One block per batch element; 256 threads; thread j owns hidden unit j and
// computes gates i,f,g,o for it (thread-local c/h update, ONE barrier/step).
// Weights per gate: 60 pairs AGPR + 32 pairs asm-pinned VGPR + 12 pairs LDS +
// 24 pairs streamed from L2 (96 KB/step, overlapped). h double-buffered in LDS.
__global__ __launch_bounds__(256, 1) void k_lstm6(
    const float* __restrict__ xg, const f16x2* __restrict__ WaG,
    const f16x2* __restrict__ WvG, const f16x2* __restrict__ WdG,
    const f16x2* __restrict__ WsG, float* __restrict__ lo) {
  int b = blockIdx.x;
  int j = threadIdx.x;

  __shared__ f16x2 wlds[12288];          // 48 KB LDS weight slice
  __shared__ f16x8 hA8[CH / 8], hB8[CH / 8];
  _Float16* hAh = (_Float16*)hA8;
  _Float16* hBh = (_Float16*)hB8;

  // LDS weight fill (one-time): 6144 uint2, 24 per thread
  {
    const uint2* src = (const uint2*)WdG;
    uint2* dst = (uint2*)wlds;
    #pragma unroll
    for (int k = 0; k < 24; ++k) dst[k * 256 + j] = src[k * 256 + j];
  }

  unsigned wA0[60], wA1[60], wA2[60], wA3[60];   // AGPR-pinned (240)
  unsigned wV0[32], wV1[32], wV2[32], wV3[32];   // VGPR-pinned (128)
  {
    const f16x8* wap = (const f16x8*)WaG;
    AFILL_G(wA0, 0) AFILL_G(wA1, 1) AFILL_G(wA2, 2) AFILL_G(wA3, 3)
    const f16x8* wvp = (const f16x8*)WvG;
    VFILL_G(wV0, 0) VFILL_G(wV1, 1) VFILL_G(wV2, 2) VFILL_G(wV3, 3)
  }

  hAh[j] = (_Float16)0.f;
  float c = 0.f;
  __syncthreads();

  const float* xgb = xg + (b * CS) * CG;
  float nx0 = xgb[j], nx1 = xgb[256 + j], nx2 = xgb[512 + j], nx3 = xgb[768 + j];
  unsigned long long wsa = (unsigned long long)WsG;
  const uint2* wl = (const uint2*)wlds;

  #pragma unroll 1
  for (int t = 0; t < CS; ++t) {
    float acc0 = nx0, acc1 = nx1, acc2 = nx2, acc3 = nx3;
    int tn = (t + 1 < CS) ? t + 1 : t;
    nx0 = xgb[tn * CG + j];       nx1 = xgb[tn * CG + 256 + j];
    nx2 = xgb[tn * CG + 512 + j]; nx3 = xgb[tn * CG + 768 + j];

    const f16x8* hs = (t & 1) ? hB8 : hA8;
    _Float16* hw = (t & 1) ? hAh : hBh;

    asm volatile("" : "+v"(wsa));          // keep stream loads per-step
    const f16x8* wsp = (const f16x8*)wsa;

    // AGPR region: chunks 0..14 (pairs 0..59 per gate)
    AGCHUNK(0)  AGCHUNK(1)  AGCHUNK(2)  AGCHUNK(3)  AGCHUNK(4)
    AGCHUNK(5)  AGCHUNK(6)  AGCHUNK(7)  AGCHUNK(8)  AGCHUNK(9)
    AGCHUNK(10) AGCHUNK(11) AGCHUNK(12) AGCHUNK(13) AGCHUNK(14)
    // VGPR region: chunks 15..22 (pairs 60..91)
    VGCHUNK(15, 0)  VGCHUNK(16, 4)  VGCHUNK(17, 8)  VGCHUNK(18, 12)
    VGCHUNK(19, 16) VGCHUNK(20, 20) VGCHUNK(21, 24) VGCHUNK(22, 28)
    // LDS region: chunks 23..25 (pairs 92..103)
    {
      f16x8 h23 = hs[23], h24 = hs[24], h25 = hs[25];
      LD4(0, PAIR0(h23), PAIR1(h23)) LD4(1, PAIR2(h23), PAIR3(h23))
      LD4(2, PAIR0(h24), PAIR1(h24)) LD4(3, PAIR2(h24), PAIR3(h24))
      LD4(4, PAIR0(h25), PAIR1(h25)) LD4(5, PAIR2(h25), PAIR3(h25))
    }
    // Stream region: chunks 26..31 (pairs 104..127)
    ST4(0) ST4(1) ST4(2) ST4(3) ST4(4) ST4(5)

    float ii = sigmf(acc0), ff = sigmf(acc1);
    float gg = tanhf(acc2), oo = sigmf(acc3);
    c = ff * c + ii * gg;
    float h = oo * tanhf(c);
    lo[(b * CS + t) * CH + j] = h;
    hw[j] = (_Float16)h;
    __syncthreads();
  }
}

// per (b,head): wS/U precompute (rows 1..127)
__global__ void k_U(const float* __restrict__ hint, const float* __restrict__ f1int,
                    const float* __restrict__ f2int, const int* __restrict__ adj,
                    float* __restrict__ U, float* __restrict__ wS) {
  int b = blockIdx.x >> 2, k = blockIdx.x & 3;
  int grp = threadIdx.x >> 6, c = threadIdx.x & 63;
  __shared__ float wbuf[4][128];
  const int adjb = b * CN * CN;
  for (int i = 1 + grp; i < 128; i += 4) {
    float f1 = f1int[k * 128 + (i - 1)];
    int j1 = 1 + c, j2 = 65 + c;
    float w1 = 0.f, w2 = 0.f;
    if (adj[adjb + i * CN + j1]) w1 = expf(leakyf(f1 + f2int[k * 128 + j1 - 1]));
    if (j2 < 128 && adj[adjb + i * CN + j2]) w2 = expf(leakyf(f1 + f2int[k * 128 + j2 - 1]));
    wbuf[grp][c] = w1;
    wbuf[grp][64 + c] = w2;
    float rs = wredf(w1 + w2);
    float acc = 0.f;
    for (int jj = 0; jj < 127; ++jj)
      acc += wbuf[grp][jj] * hint[(k * 128 + jj) * CGH + c];
    if (c == 0) wS[(b * 4 + k) * 128 + i] = rs;
    U[((b * 4 + k) * 128 + i) * CGH + c] = acc;
  }
}

// htok / f1tok / f2tok
__global__ void k_htok(const float* __restrict__ lo, const float* __restrict__ Wh,
                       const float* __restrict__ ah, float* __restrict__ htok,
                       float* __restrict__ f1tok, float* __restrict__ f2tok) {
  __shared__ float ls[8][CH];
  int m0 = blockIdx.x * 8;
  int tid = threadIdx.x;
  int k = tid >> 6, c = tid & 63;
  for (int idx = tid; idx < 8 * CH; idx += 256) {
    int r = idx >> 8, d = idx & 255;
    ls[r][d] = lo[(m0 + r) * CH + d];
  }
  __syncthreads();
  float acc[8];
  #pragma unroll
  for (int r = 0; r < 8; ++r) acc[r] = 0.f;
  #pragma unroll 4
  for (int d = 0; d < CH; ++d) {
    float w = Wh[(k * CH + d) * CGH + c];
    #pragma unroll
    for (int r = 0; r < 8; ++r) acc[r] += w * ls[r][d];
  }
  float a1 = ah[k * 128 + c], a2 = ah[k * 128 + 64 + c];
  #pragma unroll
  for (int r = 0; r < 8; ++r) {
    htok[(m0 + r) * CH + tid] = acc[r];
    float r1 = wredf(acc[r] * a1);
    float r2 = wredf(acc[r] * a2);
    if (c == 0) { f1tok[(m0 + r) * CNH + k] = r1; f2tok[(m0 + r) * CNH + k] = r2; }
  }
}

// Per-token fused GAT layer-2 + logits, two-pass, adjacency-pruned.
__global__ __launch_bounds__(256) void k_perm2(
    const float* __restrict__ lo, const float* __restrict__ htok,
    const float* __restrict__ f1tok, const float* __restrict__ f2tok,
    const float* __restrict__ hint, const float* __restrict__ f1int,
    const float* __restrict__ f2int, const float* __restrict__ U,
    const float* __restrict__ wS, const float* __restrict__ woao1,
    const float* __restrict__ woao2, const int* __restrict__ adj,
    const float* __restrict__ Wo, const float* __restrict__ Wl,
    const float* __restrict__ bl, const int* __restrict__ seq_lens,
    float* __restrict__ out) {
  int m = blockIdx.x;
  int b = m >> 6, s = m & 63;
  int tid = threadIdx.x;
  int k = tid >> 6, c = tid & 63;

  __shared__ float ht[CH];
  __shared__ float s1[CNH][CN];
  __shared__ float s2[CNH][CN];
  __shared__ float w0[CNH][CN];
  __shared__ float x10[CH];
  __shared__ float f22[CN];
  __shared__ float w2s[CN];
  __shared__ float ybuf[CH];
  __shared__ float gbuf[CH];
  __shared__ float part[2][CV];
  __shared__ int   list[CN];
  __shared__ int   cnt;
  __shared__ float f12s, f220s, den2s;

  const int adjb = b * CN * CN;
  ht[tid] = htok[m * CH + tid];
  float f1t = f1tok[m * CNH + k];
  float f2t = f2tok[m * CNH + k];

  if (k == 0) {
    int j1 = 1 + c;
    int j2 = 65 + c;
    bool fl1 = adj[adjb + j1] != 0;
    bool fl2 = (j2 < CN) && (adj[adjb + j2] != 0);
    unsigned long long b1 = __ballot(fl1);
    unsigned long long b2 = __ballot(fl2);
    unsigned long long below = (1ull << c) - 1ull;
    int n1 = __popcll(b1);
    if (fl1) list[__popcll(b1 & below)] = j1;
    if (fl2) list[n1 + __popcll(b2 & below)] = j2;
    if (c == 0) cnt = n1 + __popcll(b2);
  }

  for (int idx = tid; idx < CNH * CN; idx += 256) {
    int k2 = idx >> 7, i = idx & 127;
    if (i == 0) continue;
    float t0 = 0.f;
    if (adj[adjb + i * CN]) t0 = expf(leakyf(f1int[k2 * 128 + i - 1] + f2tok[m * CNH + k2]));
    float rd = 1.f / (wS[(b * 4 + k2) * 128 + i] + t0);
    s1[k2][i] = rd;
    s2[k2][i] = t0 * rd;
  }

  float den0;
  {
    int j1 = c, j2 = c + 64;
    float e1 = leakyf(f1t + (j1 == 0 ? f2t : f2int[k * 128 + j1 - 1]));
    float wj1 = adj[adjb + j1] ? expf(e1) : 0.f;
    float e2 = leakyf(f1t + f2int[k * 128 + j2 - 1]);
    float wj2 = adj[adjb + j2] ? expf(e2) : 0.f;
    w0[k][j1] = wj1;
    w0[k][j2] = wj2;
    den0 = wredf(wj1 + wj2);
  }
  __syncthreads();
  const int na = cnt;

  {
    float acc = w0[k][0] * ht[tid];
    #pragma unroll 4
    for (int l = 0; l < na; ++l) {
      int j = list[l];
      acc += w0[k][j] * hint[(k * 128 + j - 1) * CGH + c];
    }
    x10[tid] = eluf(acc / den0);
  }
  __syncthreads();

  if (k == 0) {
    float p = x10[c] * woao1[c] + x10[c + 64] * woao1[c + 64]
            + x10[c + 128] * woao1[c + 128] + x10[c + 192] * woao1[c + 192];
    p = wredf(p);
    if (c == 0) f12s = p;
  }
  if (k == 1) {
    float p = x10[c] * woao2[c] + x10[c + 64] * woao2[c + 64]
            + x10[c + 128] * woao2[c + 128] + x10[c + 192] * woao2[c + 192];
    p = wredf(p);
    if (c == 0) f220s = p;
  }
  for (int l = k; l < na; l += 4) {
    int j = list[l];
    float p = 0.f;
    #pragma unroll
    for (int kk = 0; kk < 4; ++kk) {
      float u = U[((b * 4 + kk) * 128 + j) * CGH + c];
      float val = eluf(u * s1[kk][j] + s2[kk][j] * ht[kk * 64 + c]);
      p += val * woao2[kk * 64 + c];
    }
    p = wredf(p);
    if (c == 0) f22[l] = p;
  }
  __syncthreads();

  float w20 = expf(leakyf(f12s + f220s));
  if (tid < na) w2s[tid] = expf(leakyf(f12s + f22[tid]));
  __syncthreads();
  if (k == 0) {
    float v = (c < na ? w2s[c] : 0.f) + (c + 64 < na ? w2s[c + 64] : 0.f);
    v = wredf(v);
    if (c == 0) den2s = v + w20;
  }

  {
    float yacc = w20 * x10[tid];
    #pragma unroll 4
    for (int l = 0; l < na; ++l) {
      int j = list[l];
      float u = U[((b * 4 + k) * 128 + j) * CGH + c];
      float val = eluf(u * s1[k][j] + s2[k][j] * ht[tid]);
      yacc += w2s[l] * val;
    }
    ybuf[tid] = yacc;
  }
  __syncthreads();

  float hacc = 0.f;
  #pragma unroll 8
  for (int kk = 0; kk < CH; ++kk) hacc += ybuf[kk] * Wo[kk * CH + tid];
  float g = eluf(hacc / den2s) + lo[m * CH + tid];
  gbuf[tid] = g;
  __syncthreads();

  {
    int col = tid & 127, hh = tid >> 7;
    float acc = 0.f;
    #pragma unroll 8
    for (int cc = hh * 128; cc < hh * 128 + 128; ++cc) acc += gbuf[cc] * Wl[cc * CV + col];
    part[hh][col] = acc;
  }
  __syncthreads();
  if (tid < CV) {
    float r = part[0][tid] + part[1][tid] + bl[tid];
    out[m * CV + tid] = (s < seq_lens[b]) ? r : 0.f;
  }
}

}  // namespace

extern "C" void kernel_launch(void* const* d_in, const int* in_sizes, int n_in,
                              void* d_out, int out_size, void* d_ws, size_t ws_size,
                              hipStream_t stream) {
  const float* hidden   = (const float*)d_in[0];
  const int*   seq_lens = (const int*)d_in[1];
  const int*   forced   = (const int*)d_in[2];
  const int*   adj      = (const int*)d_in[3];
  const float* intent   = (const float*)d_in[4];
  const float* emb      = (const float*)d_in[5];
  const float* initt    = (const float*)d_in[6];
  const float* W_ih     = (const float*)d_in[7];
  const float* W_hh     = (const float*)d_in[8];
  const float* b_ih     = (const float*)d_in[9];
  const float* b_hh     = (const float*)d_in[10];
  const float* Wh       = (const float*)d_in[11];
  const float* ah       = (const float*)d_in[12];
  const float* Wo       = (const float*)d_in[13];
  const float* ao       = (const float*)d_in[14];
  const float* Wl       = (const float*)d_in[15];
  const float* bl       = (const float*)d_in[16];
  float* out = (float*)d_out;

  float* ws    = (float*)d_ws;
  float* x     = ws;                        // 2048*384
  float* WaF   = x + CM * CDX;              // 61440 f16x2 slots
  float* WvF   = WaF + 61440;               // 32768
  float* WdF   = WvF + 32768;               // 12288
  float* WsF   = WdF + 12288;               // 24576
  float* xg    = WsF + 24576;               // 2048*1024
  float* lo    = xg + CM * CG;              // 2048*256
  float* htok  = lo + CM * CH;              // 2048*256
  float* f1tok = htok + CM * CH;            // 2048*4
  float* f2tok = f1tok + CM * CNH;          // 2048*4
  float* hint  = f2tok + CM * CNH;          // 4*128*64
  float* f1int = hint + CNH * 128 * CGH;    // 4*128
  float* f2int = f1int + CNH * 128;         // 4*128
  float* U     = f2int + CNH * 128;         // 32*4*128*64
  float* wS    = U + CB * CNH * 128 * CGH;  // 32*4*128
  float* woao1 = wS + CB * CNH * 128;       // 256
  float* woao2 = woao1 + CH;                // 256
  f16x2* Wa    = (f16x2*)WaF;
  f16x2* Wv    = (f16x2*)WvF;
  f16x2* Wd    = (f16x2*)WdF;
  f16x2* Wsb   = (f16x2*)WsF;

  k_build_x<<<(CM * CDX + 255) / 256, 256, 0, stream>>>(hidden, forced, emb, initt, x);
  k_whh_pack3<<<CG, 64, 0, stream>>>(W_hh, Wa, Wv, Wd, Wsb);
  k_hint<<<CNH * 127, 64, 0, stream>>>(intent, Wh, ah, hint, f1int, f2int);
  k_woao<<<1, 512, 0, stream>>>(Wo, ao, woao1, woao2);
  k_xg2<<<CM / 8, 256, 0, stream>>>(x, W_ih, b_ih, b_hh, xg);
  k_U<<<CB * CNH, 256, 0, stream>>>(hint, f1int, f2int, adj, U, wS);
  k_lstm6<<<CB, 256, 0, stream>>>(xg, Wa, Wv, Wd, Wsb, lo);
  k_htok<<<CM / 8, 256, 0, stream>>>(lo, Wh, ah, htok, f1tok, f2tok);
  k_perm2<<<CM, 256, 0, stream>>>(lo, htok, f1tok, f2tok, hint, f1int, f2int,
                                  U, wS, woao1, woao2, adj, Wo, Wl, bl, seq_lens, out);
}

// Round 12
// 549.699 us; speedup vs baseline: 4.3615x; 4.3615x over previous
//
#include <hip/hip_runtime.h>
#include <hip/hip_bf16.h>

namespace {

constexpr int CB   = 32;            // batch
constexpr int CS   = 64;            // seq len
constexpr int CDIN = 256;           // encoder hidden
constexpr int CH   = 256;           // LSTM hidden / GAT feature
constexpr int CE   = 128;           // embedding dim
constexpr int CV   = 128;           // vocab
constexpr int CGH  = 64;            // per-head GAT dim
constexpr int CNH  = 4;             // heads
constexpr int CN   = 128;           // graph nodes
constexpr int CDX  = CDIN + CE;     // 384 LSTM input
constexpr int CG   = 4 * CH;        // 1024 gates
constexpr int CM   = CB * CS;       // 2048 tokens
constexpr int QREG = 80;            // weight half2-pairs cached per gate (known-good r5)
constexpr int QTL  = 128 - QREG;    // 48 streamed pairs per gate

typedef _Float16 f16x2 __attribute__((ext_vector_type(2)));   // 4 BYTES = 1 float slot
typedef _Float16 f16x8 __attribute__((ext_vector_type(8)));
typedef float    f32x4 __attribute__((ext_vector_type(4)));

__device__ __forceinline__ float leakyf(float x) { return x >= 0.f ? x : 0.2f * x; }
__device__ __forceinline__ float eluf(float x)   { return x > 0.f ? x : expm1f(x); }
__device__ __forceinline__ float sigmf(float x)  { return 1.f / (1.f + expf(-x)); }
__device__ __forceinline__ float wredf(float v) {
  #pragma unroll
  for (int off = 32; off; off >>= 1) v += __shfl_xor(v, off);
  return v;
}

// Pack W_hh [1024 g][256 k] fp32 -> Wp[q][g] (q<QREG, gate-minor) and
// Wt[g][j] (j=q-QREG, gate-major f16x8-contiguous tail).  [round-5 known-good]
__global__ void k_whh_pack(const float* __restrict__ Whh, f16x2* __restrict__ Wp,
                           f16x2* __restrict__ Wt) {
  __shared__ float tile[64][257];
  int g0 = blockIdx.x * 64;
  for (int idx = threadIdx.x; idx < 64 * 256; idx += 256) {
    int gl = idx >> 8, kk = idx & 255;
    tile[gl][kk] = Whh[(g0 + gl) * CH + kk];
  }
  __syncthreads();
  for (int idx = threadIdx.x; idx < 128 * 64; idx += 256) {
    int q = idx >> 6, gl = idx & 63;
    f16x2 w = { (_Float16)tile[gl][2 * q], (_Float16)tile[gl][2 * q + 1] };
    if (q < QREG) Wp[q * CG + g0 + gl] = w;
    else          Wt[(g0 + gl) * QTL + (q - QREG)] = w;
  }
}

// hint[k][i][c] = intent[i] . Wh[k][:,c]; f1int/f2int reductions.
// Tiled: 8 intent rows staged in LDS, 16 blocks x 256 threads.
__global__ void k_hint2(const float* __restrict__ intent, const float* __restrict__ Wh,
                        const float* __restrict__ ah, float* __restrict__ hint,
                        float* __restrict__ f1int, float* __restrict__ f2int) {
  __shared__ float ls[8][CH];
  int i0 = blockIdx.x * 8;
  int tid = threadIdx.x;
  int k = tid >> 6, c = tid & 63;
  for (int idx = tid; idx < 8 * CH; idx += 256) {
    int r = idx >> 8, d = idx & 255;
    int i = i0 + r;
    ls[r][d] = (i < 127) ? intent[i * CH + d] : 0.f;
  }
  __syncthreads();
  float acc[8];
  #pragma unroll
  for (int r = 0; r < 8; ++r) acc[r] = 0.f;
  #pragma unroll 4
  for (int d = 0; d < CH; ++d) {
    float w = Wh[(k * CH + d) * CGH + c];
    #pragma unroll
    for (int r = 0; r < 8; ++r) acc[r] += w * ls[r][d];
  }
  float a1 = ah[k * 128 + c], a2 = ah[k * 128 + 64 + c];
  #pragma unroll
  for (int r = 0; r < 8; ++r) {
    int i = i0 + r;
    float r1 = wredf(acc[r] * a1);
    float r2 = wredf(acc[r] * a2);
    if (i < 127) {
      hint[(k * 128 + i) * CGH + c] = acc[r];
      if (c == 0) { f1int[k * 128 + i] = r1; f2int[k * 128 + i] = r2; }
    }
  }
}

// woao1[o] = Wo[o,:].ao[0:256]; woao2[o] = Wo[o,:].ao[256:512].
// 16 blocks x 4 waves; coalesced row reads, wave reduction per output.
__global__ void k_woao2(const float* __restrict__ Wo, const float* __restrict__ ao,
                        float* __restrict__ woao1, float* __restrict__ woao2) {
  int wave = threadIdx.x >> 6, c = threadIdx.x & 63;
  #pragma unroll
  for (int it = 0; it < 8; ++it) {
    int o = blockIdx.x * 32 + it * 4 + wave;      // 0..511
    int orow = (o < 256) ? o : o - 256;
    int abase = (o < 256) ? 0 : CH;
    const float* row = Wo + orow * CH;
    float acc = row[c] * ao[abase + c] + row[64 + c] * ao[abase + 64 + c]
              + row[128 + c] * ao[abase + 128 + c] + row[192 + c] * ao[abase + 192 + c];
    acc = wredf(acc);
    if (c == 0) {
      if (o < 256) woao1[o] = acc;
      else         woao2[o - 256] = acc;
    }
  }
}

// Fused build_x + xg: xg[m,g] = x[m,:].W_ih[g,:] + b_ih[g] + b_hh[g], where
// x[m] = [hidden[m], (s==0 ? init : emb[forced[m-1]])] built directly in LDS.
__global__ void k_xg3(const float* __restrict__ hidden, const int* __restrict__ forced,
                      const float* __restrict__ emb, const float* __restrict__ initt,
                      const float* __restrict__ Wih, const float* __restrict__ bih,
                      const float* __restrict__ bhh, float* __restrict__ xg) {
  __shared__ f32x4 xs[8][CDX / 4];  // 12 KB
  int m0 = blockIdx.x * 8;
  int tid = threadIdx.x;
  for (int idx = tid; idx < 8 * (CDX / 4); idx += 256) {
    int r = idx / (CDX / 4), q = idx - r * (CDX / 4);
    int m = m0 + r;
    f32x4 v;
    if (q < CDIN / 4) {
      v = ((const f32x4*)hidden)[m * (CDIN / 4) + q];
    } else {
      int e4 = q - CDIN / 4;                      // 0..31
      if ((m & 63) == 0) v = ((const f32x4*)initt)[e4];
      else               v = ((const f32x4*)emb)[forced[m - 1] * (CE / 4) + e4];
    }
    xs[r][q] = v;
  }
  __syncthreads();
  int g0 = tid * 4;
  float acc[8][4];
  #pragma unroll
  for (int r = 0; r < 8; ++r)
    #pragma unroll
    for (int jj = 0; jj < 4; ++jj) acc[r][jj] = 0.f;
  const f32x4* w0 = (const f32x4*)(Wih + (g0 + 0) * CDX);
  const f32x4* w1 = (const f32x4*)(Wih + (g0 + 1) * CDX);
  const f32x4* w2 = (const f32x4*)(Wih + (g0 + 2) * CDX);
  const f32x4* w3 = (const f32x4*)(Wih + (g0 + 3) * CDX);
  #pragma unroll 2
  for (int q = 0; q < CDX / 4; ++q) {
    f32x4 wa = w0[q], wb = w1[q], wc = w2[q], wd = w3[q];
    #pragma unroll
    for (int r = 0; r < 8; ++r) {
      f32x4 xv = xs[r][q];
      acc[r][0] += wa.x * xv.x + wa.y * xv.y + wa.z * xv.z + wa.w * xv.w;
      acc[r][1] += wb.x * xv.x + wb.y * xv.y + wb.z * xv.z + wb.w * xv.w;
      acc[r][2] += wc.x * xv.x + wc.y * xv.y + wc.z * xv.z + wc.w * xv.w;
      acc[r][3] += wd.x * xv.x + wd.y * xv.y + wd.z * xv.z + wd.w * xv.w;
    }
  }
  f32x4 bias = { bih[g0] + bhh[g0], bih[g0 + 1] + bhh[g0 + 1],
                 bih[g0 + 2] + bhh[g0 + 2], bih[g0 + 3] + bhh[g0 + 3] };
  #pragma unroll
  for (int r = 0; r < 8; ++r) {
    f32x4 st = { acc[r][0] + bias.x, acc[r][1] + bias.y,
                 acc[r][2] + bias.z, acc[r][3] + bias.w };
    ((f32x4*)xg)[((m0 + r) * CG + g0) / 4] = st;
  }
}

// Round-5 known-good streaming LSTM (280 us measured). Byte-identical.
__global__ __launch_bounds__(512, 2) void k_lstm4(const float* __restrict__ xg,
                                                  const f16x2* __restrict__ Wp,
                                                  const f16x2* __restrict__ Wt,
                                                  float* __restrict__ lo) {
  int b = blockIdx.x;
  int tt = threadIdx.x;
  int g0 = tt, g1 = tt + 512;
  __shared__ float gbuf[CG];
  __shared__ f16x8 hsh8[CH / 8];
  _Float16* hsh = (_Float16*)hsh8;

  f16x2 w0[QREG], w1[QREG];
  #pragma unroll
  for (int q = 0; q < QREG; ++q) {
    w0[q] = Wp[q * CG + g0];
    w1[q] = Wp[q * CG + g1];
  }
  unsigned long long wt0a = (unsigned long long)(Wt + g0 * QTL);
  unsigned long long wt1a = (unsigned long long)(Wt + g1 * QTL);

  if (tt < CH) hsh[tt] = (_Float16)0.f;
  float c = 0.f;
  __syncthreads();

  const float* xgb = xg + b * CS * CG;
  float nx0 = xgb[g0], nx1 = xgb[g1];
  for (int t = 0; t < CS; ++t) {
    float acc0 = nx0, acc1 = nx1;
    int tn = (t + 1 < CS) ? t + 1 : t;
    nx0 = xgb[tn * CG + g0];
    nx1 = xgb[tn * CG + g1];
    asm volatile("" : "+v"(wt0a), "+v"(wt1a));
    const f16x8* wt0p = (const f16x8*)wt0a;
    const f16x8* wt1p = (const f16x8*)wt1a;
    #pragma unroll
    for (int jc = 0; jc < QREG / 4; ++jc) {
      f16x8 hv = hsh8[jc];
      f16x2 ha = __builtin_shufflevector(hv, hv, 0, 1);
      f16x2 hb = __builtin_shufflevector(hv, hv, 2, 3);
      f16x2 hc = __builtin_shufflevector(hv, hv, 4, 5);
      f16x2 hd = __builtin_shufflevector(hv, hv, 6, 7);
      acc0 = __builtin_amdgcn_fdot2(w0[4 * jc + 0], ha, acc0, false);
      acc0 = __builtin_amdgcn_fdot2(w0[4 * jc + 1], hb, acc0, false);
      acc0 = __builtin_amdgcn_fdot2(w0[4 * jc + 2], hc, acc0, false);
      acc0 = __builtin_amdgcn_fdot2(w0[4 * jc + 3], hd, acc0, false);
      acc1 = __builtin_amdgcn_fdot2(w1[4 * jc + 0], ha, acc1, false);
      acc1 = __builtin_amdgcn_fdot2(w1[4 * jc + 1], hb, acc1, false);
      acc1 = __builtin_amdgcn_fdot2(w1[4 * jc + 2], hc, acc1, false);
      acc1 = __builtin_amdgcn_fdot2(w1[4 * jc + 3], hd, acc1, false);
    }
    #pragma unroll
    for (int jc = 0; jc < QTL / 4; ++jc) {
      f16x8 hv = hsh8[QREG / 4 + jc];
      f16x8 wa = wt0p[jc];
      f16x8 wb = wt1p[jc];
      f16x2 ha = __builtin_shufflevector(hv, hv, 0, 1);
      f16x2 hb = __builtin_shufflevector(hv, hv, 2, 3);
      f16x2 hc = __builtin_shufflevector(hv, hv, 4, 5);
      f16x2 hd = __builtin_shufflevector(hv, hv, 6, 7);
      acc0 = __builtin_amdgcn_fdot2(__builtin_shufflevector(wa, wa, 0, 1), ha, acc0, false);
      acc0 = __builtin_amdgcn_fdot2(__builtin_shufflevector(wa, wa, 2, 3), hb, acc0, false);
      acc0 = __builtin_amdgcn_fdot2(__builtin_shufflevector(wa, wa, 4, 5), hc, acc0, false);
      acc0 = __builtin_amdgcn_fdot2(__builtin_shufflevector(wa, wa, 6, 7), hd, acc0, false);
      acc1 = __builtin_amdgcn_fdot2(__builtin_shufflevector(wb, wb, 0, 1), ha, acc1, false);
      acc1 = __builtin_amdgcn_fdot2(__builtin_shufflevector(wb, wb, 2, 3), hb, acc1, false);
      acc1 = __builtin_amdgcn_fdot2(__builtin_shufflevector(wb, wb, 4, 5), hc, acc1, false);
      acc1 = __builtin_amdgcn_fdot2(__builtin_shufflevector(wb, wb, 6, 7), hd, acc1, false);
    }
    gbuf[g0] = acc0;
    gbuf[g1] = acc1;
    __syncthreads();
    if (tt < CH) {
      float gi = gbuf[tt], gf = gbuf[CH + tt], gg = gbuf[2 * CH + tt], go = gbuf[3 * CH + tt];
      c = sigmf(gf) * c + sigmf(gi) * tanhf(gg);
      float h = sigmf(go) * tanhf(c);
      hsh[tt] = (_Float16)h;
      lo[(b * CS + t) * CH + tt] = h;
    }
    __syncthreads();
  }
}

// per (b,head,half): wS/U precompute with hint slice + f2int staged in LDS.
__global__ __launch_bounds__(256) void k_U2(
    const float* __restrict__ hint, const float* __restrict__ f1int,
    const float* __restrict__ f2int, const int* __restrict__ adj,
    float* __restrict__ U, float* __restrict__ wS) {
  int b = blockIdx.x >> 3;          // 0..31
  int k = (blockIdx.x >> 1) & 3;    // 0..3
  int half = blockIdx.x & 1;        // 0..1
  int grp = threadIdx.x >> 6, c = threadIdx.x & 63;
  __shared__ float hs[127 * CGH];   // hint[k][0..126][:], 32 KB
  __shared__ float wbuf[4][128];
  __shared__ float f2s[128];
  for (int idx = threadIdx.x; idx < 127 * CGH; idx += 256)
    hs[idx] = hint[k * 128 * CGH + idx];
  if (threadIdx.x < 127) f2s[threadIdx.x] = f2int[k * 128 + threadIdx.x];
  __syncthreads();
  const int adjb = b * CN * CN;
  int ibeg = 1 + 64 * half;
  int iend = half ? 128 : 65;
  for (int i = ibeg + grp; i < iend; i += 4) {
    float f1 = f1int[k * 128 + (i - 1)];
    int j1 = 1 + c, j2 = 65 + c;
    float w1 = 0.f, w2 = 0.f;
    if (adj[adjb + i * CN + j1]) w1 = expf(leakyf(f1 + f2s[j1 - 1]));
    if (j2 < 128 && adj[adjb + i * CN + j2]) w2 = expf(leakyf(f1 + f2s[j2 - 1]));
    wbuf[grp][c] = w1;
    wbuf[grp][64 + c] = w2;              // slot 127 (c=63) = 0
    float rs = wredf(w1 + w2);
    float acc = 0.f;
    #pragma unroll 4
    for (int jj = 0; jj < 127; ++jj)
      acc += wbuf[grp][jj] * hs[jj * CGH + c];
    if (c == 0) wS[(b * 4 + k) * 128 + i] = rs;
    U[((b * 4 + k) * 128 + i) * CGH + c] = acc;
  }
}

// htok / f1tok / f2tok
__global__ void k_htok(const float* __restrict__ lo, const float* __restrict__ Wh,
                       const float* __restrict__ ah, float* __restrict__ htok,
                       float* __restrict__ f1tok, float* __restrict__ f2tok) {
  __shared__ float ls[8][CH];
  int m0 = blockIdx.x * 8;
  int tid = threadIdx.x;
  int k = tid >> 6, c = tid & 63;
  for (int idx = tid; idx < 8 * CH; idx += 256) {
    int r = idx >> 8, d = idx & 255;
    ls[r][d] = lo[(m0 + r) * CH + d];
  }
  __syncthreads();
  float acc[8];
  #pragma unroll
  for (int r = 0; r < 8; ++r) acc[r] = 0.f;
  #pragma unroll 4
  for (int d = 0; d < CH; ++d) {
    float w = Wh[(k * CH + d) * CGH + c];
    #pragma unroll
    for (int r = 0; r < 8; ++r) acc[r] += w * ls[r][d];
  }
  float a1 = ah[k * 128 + c], a2 = ah[k * 128 + 64 + c];
  #pragma unroll
  for (int r = 0; r < 8; ++r) {
    htok[(m0 + r) * CH + tid] = acc[r];
    float r1 = wredf(acc[r] * a1);
    float r2 = wredf(acc[r] * a2);
    if (c == 0) { f1tok[(m0 + r) * CNH + k] = r1; f2tok[(m0 + r) * CNH + k] = r2; }
  }
}

// Per-token fused GAT layer-2 + logits, two-pass, adjacency-pruned. [round-4/5 verbatim]
__global__ __launch_bounds__(256) void k_perm2(
    const float* __restrict__ lo, const float* __restrict__ htok,
    const float* __restrict__ f1tok, const float* __restrict__ f2tok,
    const float* __restrict__ hint, const float* __restrict__ f1int,
    const float* __restrict__ f2int, const float* __restrict__ U,
    const float* __restrict__ wS, const float* __restrict__ woao1,
    const float* __restrict__ woao2, const int* __restrict__ adj,
    const float* __restrict__ Wo, const float* __restrict__ Wl,
    const float* __restrict__ bl, const int* __restrict__ seq_lens,
    float* __restrict__ out) {
  int m = blockIdx.x;
  int b = m >> 6, s = m & 63;
  int tid = threadIdx.x;
  int k = tid >> 6, c = tid & 63;

  __shared__ float ht[CH];
  __shared__ float s1[CNH][CN];
  __shared__ float s2[CNH][CN];
  __shared__ float w0[CNH][CN];
  __shared__ float x10[CH];
  __shared__ float f22[CN];
  __shared__ float w2s[CN];
  __shared__ float ybuf[CH];
  __shared__ float gbuf[CH];
  __shared__ float part[2][CV];
  __shared__ int   list[CN];
  __shared__ int   cnt;
  __shared__ float f12s, f220s, den2s;

  const int adjb = b * CN * CN;
  ht[tid] = htok[m * CH + tid];
  float f1t = f1tok[m * CNH + k];
  float f2t = f2tok[m * CNH + k];

  if (k == 0) {
    int j1 = 1 + c;
    int j2 = 65 + c;
    bool fl1 = adj[adjb + j1] != 0;
    bool fl2 = (j2 < CN) && (adj[adjb + j2] != 0);
    unsigned long long b1 = __ballot(fl1);
    unsigned long long b2 = __ballot(fl2);
    unsigned long long below = (1ull << c) - 1ull;
    int n1 = __popcll(b1);
    if (fl1) list[__popcll(b1 & below)] = j1;
    if (fl2) list[n1 + __popcll(b2 & below)] = j2;
    if (c == 0) cnt = n1 + __popcll(b2);
  }

  for (int idx = tid; idx < CNH * CN; idx += 256) {
    int k2 = idx >> 7, i = idx & 127;
    if (i == 0) continue;
    float t0 = 0.f;
    if (adj[adjb + i * CN]) t0 = expf(leakyf(f1int[k2 * 128 + i - 1] + f2tok[m * CNH + k2]));
    float rd = 1.f / (wS[(b * 4 + k2) * 128 + i] + t0);
    s1[k2][i] = rd;
    s2[k2][i] = t0 * rd;
  }

  float den0;
  {
    int j1 = c, j2 = c + 64;
    float e1 = leakyf(f1t + (j1 == 0 ? f2t : f2int[k * 128 + j1 - 1]));
    float wj1 = adj[adjb + j1] ? expf(e1) : 0.f;
    float e2 = leakyf(f1t + f2int[k * 128 + j2 - 1]);
    float wj2 = adj[adjb + j2] ? expf(e2) : 0.f;
    w0[k][j1] = wj1;
    w0[k][j2] = wj2;
    den0 = wredf(wj1 + wj2);
  }
  __syncthreads();
  const int na = cnt;

  {
    float acc = w0[k][0] * ht[tid];
    #pragma unroll 4
    for (int l = 0; l < na; ++l) {
      int j = list[l];
      acc += w0[k][j] * hint[(k * 128 + j - 1) * CGH + c];
    }
    x10[tid] = eluf(acc / den0);
  }
  __syncthreads();

  if (k == 0) {
    float p = x10[c] * woao1[c] + x10[c + 64] * woao1[c + 64]
            + x10[c + 128] * woao1[c + 128] + x10[c + 192] * woao1[c + 192];
    p = wredf(p);
    if (c == 0) f12s = p;
  }
  if (k == 1) {
    float p = x10[c] * woao2[c] + x10[c + 64] * woao2[c + 64]
            + x10[c + 128] * woao2[c + 128] + x10[c + 192] * woao2[c + 192];
    p = wredf(p);
    if (c == 0) f220s = p;
  }
  for (int l = k; l < na; l += 4) {
    int j = list[l];
    float p = 0.f;
    #pragma unroll
    for (int kk = 0; kk < 4; ++kk) {
      float u = U[((b * 4 + kk) * 128 + j) * CGH + c];
      float val = eluf(u * s1[kk][j] + s2[kk][j] * ht[kk * 64 + c]);
      p += val * woao2[kk * 64 + c];
    }
    p = wredf(p);
    if (c == 0) f22[l] = p;
  }
  __syncthreads();

  float w20 = expf(leakyf(f12s + f220s));
  if (tid < na) w2s[tid] = expf(leakyf(f12s + f22[tid]));
  __syncthreads();
  if (k == 0) {
    float v = (c < na ? w2s[c] : 0.f) + (c + 64 < na ? w2s[c + 64] : 0.f);
    v = wredf(v);
    if (c == 0) den2s = v + w20;
  }

  {
    float yacc = w20 * x10[tid];
    #pragma unroll 4
    for (int l = 0; l < na; ++l) {
      int j = list[l];
      float u = U[((b * 4 + k) * 128 + j) * CGH + c];
      float val = eluf(u * s1[k][j] + s2[k][j] * ht[tid]);
      yacc += w2s[l] * val;
    }
    ybuf[tid] = yacc;
  }
  __syncthreads();

  float hacc = 0.f;
  #pragma unroll 8
  for (int kk = 0; kk < CH; ++kk) hacc += ybuf[kk] * Wo[kk * CH + tid];
  float g = eluf(hacc / den2s) + lo[m * CH + tid];
  gbuf[tid] = g;
  __syncthreads();

  {
    int col = tid & 127, hh = tid >> 7;
    float acc = 0.f;
    #pragma unroll 8
    for (int cc = hh * 128; cc < hh * 128 + 128; ++cc) acc += gbuf[cc] * Wl[cc * CV + col];
    part[hh][col] = acc;
  }
  __syncthreads();
  if (tid < CV) {
    float r = part[0][tid] + part[1][tid] + bl[tid];
    out[m * CV + tid] = (s < seq_lens[b]) ? r : 0.f;
  }
}

}  // namespace

extern "C" void kernel_launch(void* const* d_in, const int* in_sizes, int n_in,
                              void* d_out, int out_size, void* d_ws, size_t ws_size,
                              hipStream_t stream) {
  const float* hidden   = (const float*)d_in[0];
  const int*   seq_lens = (const int*)d_in[1];
  const int*   forced   = (const int*)d_in[2];
  const int*   adj      = (const int*)d_in[3];
  const float* intent   = (const float*)d_in[4];
  const float* emb      = (const float*)d_in[5];
  const float* initt    = (const float*)d_in[6];
  const float* W_ih     = (const float*)d_in[7];
  const float* W_hh     = (const float*)d_in[8];
  const float* b_ih     = (const float*)d_in[9];
  const float* b_hh     = (const float*)d_in[10];
  const float* Wh       = (const float*)d_in[11];
  const float* ah       = (const float*)d_in[12];
  const float* Wo       = (const float*)d_in[13];
  const float* ao       = (const float*)d_in[14];
  const float* Wl       = (const float*)d_in[15];
  const float* bl       = (const float*)d_in[16];
  float* out = (float*)d_out;

  // CORRECTED layout: one f16x2 (4 B) occupies ONE float slot.
  float* ws    = (float*)d_ws;
  float* WpF   = ws;                        // QREG*CG f16x2 = 81920 float slots
  float* WtF   = WpF + QREG * CG;           // CG*QTL f16x2 = 49152 float slots
  float* xg    = WtF + CG * QTL;            // 2048*1024
  float* lo    = xg + CM * CG;              // 2048*256
  float* htok  = lo + CM * CH;              // 2048*256
  float* f1tok = htok + CM * CH;            // 2048*4
  float* f2tok = f1tok + CM * CNH;          // 2048*4
  float* hint  = f2tok + CM * CNH;          // 4*128*64
  float* f1int = hint + CNH * 128 * CGH;    // 4*128
  float* f2int = f1int + CNH * 128;         // 4*128
  float* U     = f2int + CNH * 128;         // 32*4*128*64
  float* wS    = U + CB * CNH * 128 * CGH;  // 32*4*128
  float* woao1 = wS + CB * CNH * 128;       // 256
  float* woao2 = woao1 + CH;                // 256
  f16x2* Wp    = (f16x2*)WpF;
  f16x2* Wt    = (f16x2*)WtF;

  k_whh_pack<<<CG / 64, 256, 0, stream>>>(W_hh, Wp, Wt);
  k_hint2<<<16, 256, 0, stream>>>(intent, Wh, ah, hint, f1int, f2int);
  k_woao2<<<16, 256, 0, stream>>>(Wo, ao, woao1, woao2);
  k_xg3<<<CM / 8, 256, 0, stream>>>(hidden, forced, emb, initt, W_ih, b_ih, b_hh, xg);
  k_U2<<<CB * CNH * 2, 256, 0, stream>>>(hint, f1int, f2int, adj, U, wS);
  k_lstm4<<<CB, 512, 0, stream>>>(xg, Wp, Wt, lo);
  k_htok<<<CM / 8, 256, 0, stream>>>(lo, Wh, ah, htok, f1tok, f2tok);
  k_perm2<<<CM, 256, 0, stream>>>(lo, htok, f1tok, f2tok, hint, f1int, f2int,
                                  U, wS, woao1, woao2, adj, Wo, Wl, bl, seq_lens, out);
}